// Round 5
// baseline (241.140 us; speedup 1.0000x reference)
//
#include <hip/hip_runtime.h>

typedef unsigned short UST;
typedef __attribute__((ext_vector_type(8))) short bf16x8;
typedef __attribute__((ext_vector_type(8))) unsigned short us8;
typedef __attribute__((ext_vector_type(4))) float f32x4;

__device__ __forceinline__ UST f2bf(float f) {
  union { float f; unsigned int u; } x; x.f = f;
  unsigned int r = x.u + 0x7fffu + ((x.u >> 16) & 1u);
  return (UST)(r >> 16);
}
__device__ __forceinline__ float bf2f(UST h) {
  union { unsigned int u; float f; } x; x.u = ((unsigned int)h) << 16;
  return x.f;
}

__device__ __forceinline__ void sync_lds() {
  asm volatile("s_waitcnt lgkmcnt(0)\n\ts_barrier" ::: "memory");
}
__device__ __forceinline__ void barrier_nowait() {
  asm volatile("s_barrier" ::: "memory");
}

typedef const __attribute__((address_space(1))) void g_void;
typedef __attribute__((address_space(3))) void lds_void;
__device__ __forceinline__ void gload16(const UST* g, UST* l) {
  __builtin_amdgcn_global_load_lds((g_void*)g, (lds_void*)l, 16, 0, 0);
}

// ---- prep: GroupNorm (single pass) + weight conversion + zero l ------------
__global__ __launch_bounds__(256) void prep(
    const float* __restrict__ inp, const float* __restrict__ gamma,
    const float* __restrict__ beta, UST* __restrict__ Xnt,
    const float4* __restrict__ wq, const float4* __restrict__ wk,
    const float4* __restrict__ wv, const float4* __restrict__ wo,
    ushort4* __restrict__ oqkv, ushort4* __restrict__ owo,
    const float4* __restrict__ bq4, const float4* __restrict__ bk4,
    const float4* __restrict__ bv4, float4* __restrict__ bqkv4,
    float4* __restrict__ l4) {
  const int tid = threadIdx.x;
  if (blockIdx.x >= 768) {
    int i = (blockIdx.x - 768) * 256 + tid;
    l4[i] = make_float4(0.f, 0.f, 0.f, 0.f);
    return;
  }
  if (blockIdx.x >= 512) {
    const int wb = blockIdx.x - 512;
    int i = wb * 256 + tid;
    float4 v;
    v = wq[i]; oqkv[i]          = make_ushort4(f2bf(v.x), f2bf(v.y), f2bf(v.z), f2bf(v.w));
    v = wk[i]; oqkv[i + 65536]  = make_ushort4(f2bf(v.x), f2bf(v.y), f2bf(v.z), f2bf(v.w));
    v = wv[i]; oqkv[i + 131072] = make_ushort4(f2bf(v.x), f2bf(v.y), f2bf(v.z), f2bf(v.w));
    v = wo[i]; owo[i]           = make_ushort4(f2bf(v.x), f2bf(v.y), f2bf(v.z), f2bf(v.w));
    if (wb < 2) {
      int t = wb * 256 + tid;
      if (t < 384) bqkv4[t] = (t < 128) ? bq4[t] : (t < 256 ? bk4[t - 128] : bv4[t - 256]);
    }
    return;
  }
  const int g = blockIdx.x & 31, b = blockIdx.x >> 5;
  const float4* p4 = (const float4*)(inp + ((size_t)b * 32 + g) * 16384);
  float x[16][4];
  float s = 0.f, ss = 0.f;
#pragma unroll
  for (int i = 0; i < 16; i++) {
    float4 t = p4[tid + i * 256];
    x[i][0] = t.x; x[i][1] = t.y; x[i][2] = t.z; x[i][3] = t.w;
    s += t.x + t.y + t.z + t.w;
    ss += t.x * t.x + t.y * t.y + t.z * t.z + t.w * t.w;
  }
  for (int o = 32; o >= 1; o >>= 1) { s += __shfl_xor(s, o); ss += __shfl_xor(ss, o); }
  __shared__ float red[8];
  __shared__ float mu_s, rstd_s;
  const int w = tid >> 6;
  if ((tid & 63) == 0) { red[w * 2] = s; red[w * 2 + 1] = ss; }
  __syncthreads();
  if (tid == 0) {
    float S1 = red[0] + red[2] + red[4] + red[6];
    float S2 = red[1] + red[3] + red[5] + red[7];
    float mu = S1 * (1.f / 16384.f);
    float var = S2 * (1.f / 16384.f) - mu * mu;
    mu_s = mu; rstd_s = rsqrtf(var + 1e-6f);
  }
  __syncthreads();
  const float mu = mu_s, rstd = rstd_s;
#pragma unroll
  for (int o2 = 0; o2 < 2; o2++) {
    const int ccg = g * 2 + o2;
    float sc[8], sh[8];
#pragma unroll
    for (int j = 0; j < 8; j++) {
      int ch = ccg * 8 + j;
      sc[j] = gamma[ch] * rstd;
      sh[j] = beta[ch] - mu * sc[j];
    }
#pragma unroll
    for (int m = 0; m < 4; m++) {
      us8 v;
#pragma unroll
      for (int j = 0; j < 8; j++) v[j] = f2bf(x[o2 * 8 + j][m] * sc[j] + sh[j]);
      *(us8*)(Xnt + (size_t)b * 524288 + (size_t)ccg * 8192 + (size_t)(4 * tid + m) * 8) = v;
    }
  }
}

// ---- gemm8p: 256x256 8-wave 4-phase(BK=64) deep-pipelined GEMM -------------
// C[i][j] = sum_k A[i][k]*B[j][k]. 512 thr = 8 waves (2M x 4N), per-wave
// 128x64 output = acc[8][4]. BK=64 (2 kslots of 32). LDS: 2 dbuf x 64KB
// {A 256x64 | B 256x64}, quarters of 64 rows. Per K-tile 4 phases, phase p
// computes quadrant (ih=p>>1, jh=p&1): 12 ds_read_b128 + 2 gload_lds + 2
// barriers + lgkmcnt(0) + 16 MFMA (setprio-wrapped). Counted vmcnt, never
// drained mid-loop: staging order per tile [Aq0,Aq2,Bq0..3,Aq1,Aq3];
// vmcnt(2) at ph3-end (next tile's Aq0,Aq2,B ready; A-late still flying),
// vmcnt(4) at ph1-end (this tile's Aq1,Aq3 ready before ph2 reads them).
// Layouts: AR=1 (Xnt): A quarter = [8 kc][64 rows][8] (kc-plane, coalesced
// 1KB/instr, conflict-free). AR=0 / B: [64 rows][8 slots][8] with slot =
// kc ^ (row&7) XOR content swizzle applied on the GLOBAL src (LDS linear,
// rule #21) and on ds_read -> 2-way floor.
// EPI 6: bf16 +bias[col]; n0<1024 -> QKt; else V transposed (c,m).
// EPI 7: P = exp(acc*scale) bf16 + per-row sums atomicAdd into l.
template <int EPI, int NT, int AR>
__global__ __launch_bounds__(512, 2) void gemm8p(
    const UST* __restrict__ A, const UST* __restrict__ B, void* __restrict__ C,
    const float* __restrict__ bias, const float* __restrict__ extra, float scale,
    int K, int ldc, int rsA, int csA, long ssA, int rsB, long ssB,
    long zA, long zB, long zC) {
  __shared__ __align__(16) UST buf[65536];  // 128 KiB

  const int tid = threadIdx.x;
  // XCD-aware swizzle over A-tiles (T = gridDim.y*gridDim.z, multiple of 8)
  int lin = blockIdx.x + NT * (blockIdx.y + gridDim.y * blockIdx.z);
  int T = gridDim.y * gridDim.z;
  int per = T >> 3;
  int g = lin & 7, idx = lin >> 3;
  int at = g * per + idx / NT;
  int x = idx % NT;
  const int m0 = (at % gridDim.y) * 256;
  const int z = at / gridDim.y;
  const int n0 = x * 256;

  const UST* Ab = A + (long)z * zA;
  const UST* Bb = B + (long)z * zB;

  const int w = tid >> 6, lane = tid & 63;
  const int quad = lane >> 4, l16 = lane & 15;
  const int wr = w >> 2, wc = w & 3;  // 2x4 waves, each 128(m) x 64(n)

  f32x4 acc[8][4];
#pragma unroll
  for (int i = 0; i < 8; i++)
#pragma unroll
    for (int j = 0; j < 4; j++) acc[i][j] = f32x4{0.f, 0.f, 0.f, 0.f};

  // ---- staging pointers: 8 positions/wave, 1KB each ----
  // pos: 0=Aq0 1=Aq2 2=Bq0 3=Bq1 4=Bq2 5=Bq3 6=Aq1 7=Aq3
  const UST* gp[8];
  int lo[8];
  {
    const int lr = w * 8 + (lane >> 3);
    const int kcl = (lane & 7) ^ (lane >> 3);
#pragma unroll
    for (int p = 0; p < 8; p++) {
      int q;
      bool isA;
      if (p == 0) { q = 0; isA = true; }
      else if (p == 1) { q = 2; isA = true; }
      else if (p == 6) { q = 1; isA = true; }
      else if (p == 7) { q = 3; isA = true; }
      else { q = p - 2; isA = false; }
      if (isA) {
        if (AR) gp[p] = Ab + (size_t)(m0 + q * 64 + lane) * rsA + (size_t)w * csA;
        else    gp[p] = Ab + (size_t)(m0 + q * 64 + lr) * rsA + (size_t)kcl * csA;
        lo[p] = q * 4096 + w * 512;
      } else {
        gp[p] = Bb + (size_t)(n0 + q * 64 + lr) * rsB + (size_t)kcl * 8;
        lo[p] = 16384 + q * 4096 + w * 512;
      }
    }
  }

  // ---- ds_read offsets (UST, within one dbuf) ----
  int aoffs[8][2], boffs[4][2];
#pragma unroll
  for (int i = 0; i < 8; i++) {
    int R = wr * 128 + i * 16 + l16;
    int q = R >> 6, lr = R & 63;
#pragma unroll
    for (int ks = 0; ks < 2; ks++) {
      int kc = ks * 4 + quad;
      aoffs[i][ks] = AR ? (q * 4096 + (kc * 64 + lr) * 8)
                        : (q * 4096 + (lr * 8 + (kc ^ (lr & 7))) * 8);
    }
  }
#pragma unroll
  for (int j = 0; j < 4; j++) {
    int R = wc * 64 + j * 16 + l16;
    int q = R >> 6, lr = R & 63;
#pragma unroll
    for (int ks = 0; ks < 2; ks++) {
      int kc = ks * 4 + quad;
      boffs[j][ks] = 16384 + q * 4096 + (lr * 8 + (kc ^ (lr & 7))) * 8;
    }
  }

  const int nk = K >> 6;  // K-tiles of 64

#define STG(P, SS) { gload16(gp[P], lb + lo[P]); gp[P] += (SS); }

  // prologue: stage tile 0 into buf0, wait early quarters, barrier
  {
    UST* lb = buf;
    STG(0, ssA) STG(1, ssA) STG(2, ssB) STG(3, ssB)
    STG(4, ssB) STG(5, ssB) STG(6, ssA) STG(7, ssA)
  }
  asm volatile("s_waitcnt vmcnt(2)" ::: "memory");
  barrier_nowait();

#define PH(IH, JH, P0, P1, SS0, SS1, VME)                                     \
  {                                                                           \
    bf16x8 af[4][2], bfr[2][2];                                               \
    _Pragma("unroll") for (int il = 0; il < 4; il++)                          \
      _Pragma("unroll") for (int ks = 0; ks < 2; ks++)                        \
        af[il][ks] = *(const bf16x8*)(cb + aoffs[(IH)*4 + il][ks]);           \
    _Pragma("unroll") for (int jl = 0; jl < 2; jl++)                          \
      _Pragma("unroll") for (int ks = 0; ks < 2; ks++)                        \
        bfr[jl][ks] = *(const bf16x8*)(cb + boffs[(JH)*2 + jl][ks]);          \
    if (stg) { STG(P0, SS0) STG(P1, SS1) }                                    \
    barrier_nowait();                                                         \
    asm volatile("s_waitcnt lgkmcnt(0)" ::: "memory");                        \
    __builtin_amdgcn_sched_barrier(0);                                        \
    __builtin_amdgcn_s_setprio(1);                                            \
    _Pragma("unroll") for (int il = 0; il < 4; il++)                          \
      _Pragma("unroll") for (int jl = 0; jl < 2; jl++)                        \
        _Pragma("unroll") for (int ks = 0; ks < 2; ks++)                      \
          acc[(IH)*4 + il][(JH)*2 + jl] = __builtin_amdgcn_mfma_f32_16x16x32_bf16( \
              af[il][ks], bfr[jl][ks], acc[(IH)*4 + il][(JH)*2 + jl], 0, 0, 0);    \
    __builtin_amdgcn_s_setprio(0);                                            \
    VME;                                                                      \
    barrier_nowait();                                                         \
  }

  for (int t = 0; t < nk; ++t) {
    const UST* cb = buf + (t & 1) * 32768;
    UST* lb = buf + ((t + 1) & 1) * 32768;
    const bool stg = (t + 1 < nk);
    PH(0, 0, 0, 1, ssA, ssA, {})
    PH(0, 1, 2, 3, ssB, ssB, {
      if (stg) { asm volatile("s_waitcnt vmcnt(4)" ::: "memory"); }
      else     { asm volatile("s_waitcnt vmcnt(0)" ::: "memory"); }
    })
    PH(1, 0, 4, 5, ssB, ssB, {})
    PH(1, 1, 6, 7, ssA, ssA, {
      if (stg) { asm volatile("s_waitcnt vmcnt(2)" ::: "memory"); }
    })
  }
#undef PH
#undef STG

  // ---- epilogues (buf free; last trailing barrier passed) ----
  // C/D layout: row = wr*128 + i*16 + quad*4 + r, col = wc*64 + j*16 + l16
  if constexpr (EPI == 7) {
    UST* Cb = (UST*)C + (long)z * zC;
    float* lrow = (float*)extra + (long)z * 1024;
#pragma unroll
    for (int h = 0; h < 2; ++h) {
      if (h) barrier_nowait();
      if (wr == h) {
#pragma unroll
        for (int i = 0; i < 8; i++)
#pragma unroll
          for (int j = 0; j < 4; j++)
#pragma unroll
            for (int r = 0; r < 4; r++) {
              float v = __expf(acc[i][j][r] * scale);
              buf[(i * 16 + quad * 4 + r) * 260 + wc * 64 + j * 16 + l16] = f2bf(v);
            }
      }
      sync_lds();
#pragma unroll
      for (int it = 0; it < 8; ++it) {
        int q = tid + it * 512;
        int row = q >> 5, colc = q & 31;
        us8 v = *(us8*)&buf[row * 260 + colc * 8];
        *(us8*)&Cb[(size_t)(m0 + h * 128 + row) * ldc + n0 + colc * 8] = v;
        float s = 0.f;
#pragma unroll
        for (int jj = 0; jj < 8; jj++) s += bf2f(v[jj]);
        s += __shfl_xor(s, 16); s += __shfl_xor(s, 8);
        s += __shfl_xor(s, 4); s += __shfl_xor(s, 2); s += __shfl_xor(s, 1);
        if ((lane & 31) == 0) atomicAdd(&lrow[m0 + h * 128 + row], s);
      }
    }
  } else {  // EPI 6
    const bool vreg = (n0 >= 1024);
    if (!vreg) {
      UST* Cb = (UST*)C + (long)z * zC;
#pragma unroll
      for (int h = 0; h < 2; ++h) {
        if (h) barrier_nowait();
        if (wr == h) {
#pragma unroll
          for (int i = 0; i < 8; i++)
#pragma unroll
            for (int j = 0; j < 4; j++) {
              const float bc = bias[n0 + wc * 64 + j * 16 + l16];
#pragma unroll
              for (int r = 0; r < 4; r++)
                buf[(i * 16 + quad * 4 + r) * 260 + wc * 64 + j * 16 + l16] =
                    f2bf(acc[i][j][r] + bc);
            }
        }
        sync_lds();
#pragma unroll
        for (int it = 0; it < 8; ++it) {
          int q = tid + it * 512;
          int row = q >> 5, colc = q & 31;
          us8 v = *(us8*)&buf[row * 260 + colc * 8];
          *(us8*)&Cb[(size_t)(m0 + h * 128 + row) * ldc + n0 + colc * 8] = v;
        }
      }
    } else {
      // V: transpose to (c, m); phase h stages C-half h (cols h*128..+128)
      UST* Vb = (UST*)extra + (long)z * 524288;
#pragma unroll
      for (int h = 0; h < 2; ++h) {
        if (h) barrier_nowait();
        if ((wc >> 1) == h) {
#pragma unroll
          for (int i = 0; i < 8; i++)
#pragma unroll
            for (int j = 0; j < 4; j++) {
              const float bc = bias[n0 + wc * 64 + j * 16 + l16];
              const int Cl = (wc & 1) * 64 + j * 16 + l16;
              const int R0 = wr * 128 + i * 16 + quad * 4;
              ushort4 sv;
              sv.x = f2bf(acc[i][j][0] + bc);
              sv.y = f2bf(acc[i][j][1] + bc);
              sv.z = f2bf(acc[i][j][2] + bc);
              sv.w = f2bf(acc[i][j][3] + bc);
              *(ushort4*)&buf[Cl * 260 + R0] = sv;
            }
        }
        sync_lds();
#pragma unroll
        for (int it = 0; it < 8; ++it) {
          int q = tid + it * 512;
          int Cl = q >> 5, mc = q & 31;
          us8 v = *(us8*)&buf[Cl * 260 + mc * 8];
          *(us8*)&Vb[(size_t)(n0 - 1024 + h * 128 + Cl) * 1024 + m0 + mc * 8] = v;
        }
      }
    }
  }
}

// ---- gemm_bt v5 (proven): 128x128, 4 waves, gload_lds, depth-2 vmcnt(4) ----
// Kept for EPI 8 (PV/l) and EPI 4 (out-proj + residual).
template <int EPI, int NT, int AR, int BR>
__global__ __launch_bounds__(256, 4) void gemm_bt(
    const UST* __restrict__ A, const UST* __restrict__ B, void* __restrict__ C,
    const float* __restrict__ bias, const float* __restrict__ extra, float scale,
    int K, int ldc,
    int rsA, int csA, int ssA, int rsB, int csB, int ssB,
    long zA, long zB, long zC) {
  __shared__ __align__(16) UST buf[16384];

  const int tid = threadIdx.x;
  int m0, n0, z;
  if constexpr (NT > 0) {
    int lin = blockIdx.x + NT * (blockIdx.y + gridDim.y * blockIdx.z);
    int T = gridDim.y * gridDim.z;
    int per = T >> 3;
    int g = lin & 7, idx = lin >> 3;
    int at = g * per + idx / NT;
    int x = idx % NT;
    m0 = (at % gridDim.y) * 128; z = at / gridDim.y; n0 = x * 128;
  } else {
    m0 = blockIdx.y * 128; n0 = blockIdx.x * 128; z = blockIdx.z;
  }
  const UST* Ab = A + (long)z * zA;
  const UST* Bb = B + (long)z * zB;

  const int w = tid >> 6, lane = tid & 63;
  const int quad = lane >> 4, l16 = lane & 15;
  const int wm = w >> 1, wn = w & 1;

  f32x4 acc[4][4];
#pragma unroll
  for (int i = 0; i < 4; i++)
#pragma unroll
    for (int j = 0; j < 4; j++) acc[i][j] = f32x4{0.f, 0.f, 0.f, 0.f};

  const UST* gA[2];
  const UST* gB[2];
#pragma unroll
  for (int t = 0; t < 2; t++) {
    int q = t * 256 + w * 64 + lane;
    int row, kc;
    if constexpr (AR) { kc = q >> 7; row = q & 127; }
    else {
      row = q >> 2; int kk = q & 3;
      kc = kk ^ (((row >> 1) ^ (row >> 3)) & 3);
    }
    gA[t] = Ab + (size_t)(m0 + row) * rsA + (size_t)kc * csA;
  }
#pragma unroll
  for (int t = 0; t < 2; t++) {
    int q = t * 256 + w * 64 + lane;
    int row, kc;
    if constexpr (BR) { kc = q >> 7; row = q & 127; }
    else {
      row = q >> 2; int kk = q & 3;
      kc = kk ^ (((row >> 1) ^ (row >> 3)) & 3);
    }
    gB[t] = Bb + (size_t)(n0 + row) * rsB + (size_t)kc * csB;
  }
  int aoff[4], boff[4];
#pragma unroll
  for (int i = 0; i < 4; i++) {
    int R = wm * 64 + i * 16 + l16;
    if constexpr (AR) aoff[i] = quad * 1024 + R * 8;
    else {
      int s = ((R >> 1) ^ (R >> 3)) & 3;
      aoff[i] = R * 32 + (quad ^ s) * 8;
    }
  }
#pragma unroll
  for (int j = 0; j < 4; j++) {
    int R = wn * 64 + j * 16 + l16;
    if constexpr (BR) boff[j] = quad * 1024 + R * 8;
    else {
      int s = ((R >> 1) ^ (R >> 3)) & 3;
      boff[j] = R * 32 + (quad ^ s) * 8;
    }
  }

  const int nk = K >> 5;

#define STAGE(bb)                                   \
  {                                                 \
    UST* sA = buf + (bb) * 8192;                    \
    UST* sB = sA + 4096;                            \
    _Pragma("unroll") for (int t = 0; t < 2; t++) { \
      gload16(gA[t], sA + t * 2048 + w * 512);      \
      gA[t] += ssA;                                 \
    }                                               \
    _Pragma("unroll") for (int t = 0; t < 2; t++) { \
      gload16(gB[t], sB + t * 2048 + w * 512);      \
      gB[t] += ssB;                                 \
    }                                               \
  }

  STAGE(0)
  STAGE(1)

  for (int k = 0; k < nk; ++k) {
    if (k + 1 < nk) asm volatile("s_waitcnt vmcnt(4)" ::: "memory");
    else            asm volatile("s_waitcnt vmcnt(0)" ::: "memory");
    barrier_nowait();
    const UST* cA = buf + (k & 1) * 8192;
    const UST* cB = cA + 4096;
    bf16x8 af[4], bfr[4];
#pragma unroll
    for (int i = 0; i < 4; i++) af[i] = *(const bf16x8*)(cA + aoff[i]);
#pragma unroll
    for (int j = 0; j < 4; j++) bfr[j] = *(const bf16x8*)(cB + boff[j]);
    __builtin_amdgcn_s_setprio(1);
#pragma unroll
    for (int i = 0; i < 4; i++)
#pragma unroll
      for (int j = 0; j < 4; j++)
        acc[i][j] = __builtin_amdgcn_mfma_f32_16x16x32_bf16(af[i], bfr[j], acc[i][j], 0, 0, 0);
    __builtin_amdgcn_s_setprio(0);
    if (k + 2 < nk) {
      sync_lds();
      STAGE(k & 1)
    }
  }
  sync_lds();

  if constexpr (EPI == 4) {
    float* fbuf = (float*)buf;
    float* Cb = (float*)C + (long)z * zC;
    const float* Eb = extra + (long)z * zC;
#pragma unroll
    for (int p = 0; p < 4; ++p) {
      if (p) barrier_nowait();
      if (wm == (p >> 1)) {
#pragma unroll
        for (int ii = 0; ii < 2; ii++) {
          const int i = (p & 1) * 2 + ii;
#pragma unroll
          for (int j = 0; j < 4; j++)
#pragma unroll
            for (int r = 0; r < 4; r++)
              fbuf[(ii * 16 + quad * 4 + r) * 132 + wn * 64 + j * 16 + l16] = acc[i][j][r];
        }
      }
      sync_lds();
#pragma unroll
      for (int it = 0; it < 4; ++it) {
        int q = tid + it * 256;
        int row = q >> 5, colc = q & 31;
        int gr = m0 + p * 32 + row;
        size_t off = (size_t)gr * ldc + n0 + colc * 4;
        float4 v = *(float4*)&fbuf[row * 132 + colc * 4];
        float4 e = *(const float4*)&Eb[off];
        float bb = bias[gr];
        v.x += bb + e.x; v.y += bb + e.y; v.z += bb + e.z; v.w += bb + e.w;
        *(float4*)&Cb[off] = v;
      }
    }
  } else if constexpr (EPI == 8) {
    UST* Cb = (UST*)C + (long)z * zC;
    const float* lrow = bias + (long)z * 1024;
#pragma unroll
    for (int h = 0; h < 2; ++h) {
      if (h) barrier_nowait();
      if (wm == h) {
#pragma unroll
        for (int i = 0; i < 4; i++) {
          float rs[4];
#pragma unroll
          for (int r = 0; r < 4; r++)
            rs[r] = 1.0f / lrow[m0 + h * 64 + i * 16 + quad * 4 + r];
#pragma unroll
          for (int j = 0; j < 4; j++)
#pragma unroll
            for (int r = 0; r < 4; r++)
              buf[(i * 16 + quad * 4 + r) * 136 + wn * 64 + j * 16 + l16] =
                  f2bf(acc[i][j][r] * rs[r]);
        }
      }
      sync_lds();
#pragma unroll
      for (int it = 0; it < 4; ++it) {
        int q = tid + it * 256;
        int row = q >> 4, colc = q & 15;
        us8 v = *(us8*)&buf[row * 136 + colc * 8];
        *(us8*)&Cb[(size_t)(m0 + h * 64 + row) * ldc + n0 + colc * 8] = v;
      }
    }
  }
#undef STAGE
}

extern "C" void kernel_launch(void* const* d_in, const int* in_sizes, int n_in,
                              void* d_out, int out_size, void* d_ws, size_t ws_size,
                              hipStream_t stream) {
  const float* inp   = (const float*)d_in[0];
  const float* gamma = (const float*)d_in[1];
  const float* beta  = (const float*)d_in[2];
  const float* Wq    = (const float*)d_in[3];
  const float* bq    = (const float*)d_in[4];
  const float* Wk    = (const float*)d_in[5];
  const float* bk    = (const float*)d_in[6];
  const float* Wv    = (const float*)d_in[7];
  const float* bv    = (const float*)d_in[8];
  const float* Wo    = (const float*)d_in[9];
  const float* bo    = (const float*)d_in[10];
  float* out = (float*)d_out;
  char* ws = (char*)d_ws;

  UST*   Xnt   = (UST*)(ws);                           // 16 MB; reused as At
  UST*   QKt   = (UST*)(ws + ((size_t)16 << 20));      // 32 MB (b,n,1024)
  UST*   V     = (UST*)(ws + ((size_t)48 << 20));      // 16 MB (b,c,m)
  UST*   P     = (UST*)(ws + ((size_t)64 << 20));      // 32 MB (b,n,m)
  float* bqkv  = (float*)(ws + ((size_t)96 << 20));    // 6 KB
  UST*   Wqkvb = (UST*)(ws + ((size_t)96 << 20) + 8192);  // 1.5 MB
  UST*   Wob   = Wqkvb + 786432;                       // 512 KB
  float* l     = (float*)(ws + ((size_t)100 << 20));   // 64 KB
  UST*   At    = Xnt;

  prep<<<784, 256, 0, stream>>>(
      inp, gamma, beta, Xnt,
      (const float4*)Wq, (const float4*)Wk, (const float4*)Wv, (const float4*)Wo,
      (ushort4*)Wqkvb, (ushort4*)Wob,
      (const float4*)bq, (const float4*)bk, (const float4*)bv, (float4*)bqkv,
      (float4*)l);

  // QKV: 256x256 tiles; cols 0..1023 -> QKt ; cols 1024..1535 -> V^T
  gemm8p<6, 6, 1><<<dim3(6, 4, 16), 512, 0, stream>>>(
      Xnt, Wqkvb, QKt, bqkv, (const float*)V, 1.f,
      512, 1024, 8, 8192, 65536, 512, 64, 524288, 0, 1048576);
  // P = exp(Q K^T * scale), row sums -> l
  gemm8p<7, 4, 0><<<dim3(4, 4, 16), 512, 0, stream>>>(
      QKt, QKt + 512, P, nullptr, (const float*)l, 0.04419417382415922f,
      512, 1024, 1024, 8, 64, 1024, 64, 1048576, 1048576, 1048576);
  // At = (P V^T) / l[row]
  gemm_bt<8, 4, 0, 0><<<dim3(4, 8, 16), 256, 0, stream>>>(
      P, V, At, (const float*)l, nullptr, 1.f,
      1024, 512, 1024, 8, 32, 1024, 8, 32, 1048576, 524288, 524288);
  // out = Wo At^T + bo[row] + inp
  gemm_bt<4, 8, 0, 0><<<dim3(8, 4, 16), 256, 0, stream>>>(
      Wob, At, out, bo, inp, 1.f,
      512, 1024, 512, 8, 32, 512, 8, 32, 0, 524288, 524288);
}

// Round 6
// 214.982 us; speedup vs baseline: 1.1217x; 1.1217x over previous
//
#include <hip/hip_runtime.h>

typedef unsigned short UST;
typedef __attribute__((ext_vector_type(8))) short bf16x8;
typedef __attribute__((ext_vector_type(8))) unsigned short us8;
typedef __attribute__((ext_vector_type(4))) float f32x4;

__device__ __forceinline__ UST f2bf(float f) {
  union { float f; unsigned int u; } x; x.f = f;
  unsigned int r = x.u + 0x7fffu + ((x.u >> 16) & 1u);
  return (UST)(r >> 16);
}
__device__ __forceinline__ float bf2f(UST h) {
  union { unsigned int u; float f; } x; x.u = ((unsigned int)h) << 16;
  return x.f;
}

__device__ __forceinline__ void sync_lds() {
  asm volatile("s_waitcnt lgkmcnt(0)\n\ts_barrier" ::: "memory");
}
__device__ __forceinline__ void barrier_nowait() {
  asm volatile("s_barrier" ::: "memory");
}

typedef const __attribute__((address_space(1))) void g_void;
typedef __attribute__((address_space(3))) void lds_void;
__device__ __forceinline__ void gload16(const UST* g, UST* l) {
  __builtin_amdgcn_global_load_lds((g_void*)g, (lds_void*)l, 16, 0, 0);
}

// ---- prep: GroupNorm (single pass) + weight conversion + zero l ------------
__global__ __launch_bounds__(256) void prep(
    const float* __restrict__ inp, const float* __restrict__ gamma,
    const float* __restrict__ beta, UST* __restrict__ Xnt,
    const float4* __restrict__ wq, const float4* __restrict__ wk,
    const float4* __restrict__ wv, const float4* __restrict__ wo,
    ushort4* __restrict__ oqkv, ushort4* __restrict__ owo,
    const float4* __restrict__ bq4, const float4* __restrict__ bk4,
    const float4* __restrict__ bv4, float4* __restrict__ bqkv4,
    float4* __restrict__ l4) {
  const int tid = threadIdx.x;
  if (blockIdx.x >= 768) {
    int i = (blockIdx.x - 768) * 256 + tid;
    l4[i] = make_float4(0.f, 0.f, 0.f, 0.f);
    return;
  }
  if (blockIdx.x >= 512) {
    const int wb = blockIdx.x - 512;
    int i = wb * 256 + tid;
    float4 v;
    v = wq[i]; oqkv[i]          = make_ushort4(f2bf(v.x), f2bf(v.y), f2bf(v.z), f2bf(v.w));
    v = wk[i]; oqkv[i + 65536]  = make_ushort4(f2bf(v.x), f2bf(v.y), f2bf(v.z), f2bf(v.w));
    v = wv[i]; oqkv[i + 131072] = make_ushort4(f2bf(v.x), f2bf(v.y), f2bf(v.z), f2bf(v.w));
    v = wo[i]; owo[i]           = make_ushort4(f2bf(v.x), f2bf(v.y), f2bf(v.z), f2bf(v.w));
    if (wb < 2) {
      int t = wb * 256 + tid;
      if (t < 384) bqkv4[t] = (t < 128) ? bq4[t] : (t < 256 ? bk4[t - 128] : bv4[t - 256]);
    }
    return;
  }
  const int g = blockIdx.x & 31, b = blockIdx.x >> 5;
  const float4* p4 = (const float4*)(inp + ((size_t)b * 32 + g) * 16384);
  float x[16][4];
  float s = 0.f, ss = 0.f;
#pragma unroll
  for (int i = 0; i < 16; i++) {
    float4 t = p4[tid + i * 256];
    x[i][0] = t.x; x[i][1] = t.y; x[i][2] = t.z; x[i][3] = t.w;
    s += t.x + t.y + t.z + t.w;
    ss += t.x * t.x + t.y * t.y + t.z * t.z + t.w * t.w;
  }
  for (int o = 32; o >= 1; o >>= 1) { s += __shfl_xor(s, o); ss += __shfl_xor(ss, o); }
  __shared__ float red[8];
  __shared__ float mu_s, rstd_s;
  const int w = tid >> 6;
  if ((tid & 63) == 0) { red[w * 2] = s; red[w * 2 + 1] = ss; }
  __syncthreads();
  if (tid == 0) {
    float S1 = red[0] + red[2] + red[4] + red[6];
    float S2 = red[1] + red[3] + red[5] + red[7];
    float mu = S1 * (1.f / 16384.f);
    float var = S2 * (1.f / 16384.f) - mu * mu;
    mu_s = mu; rstd_s = rsqrtf(var + 1e-6f);
  }
  __syncthreads();
  const float mu = mu_s, rstd = rstd_s;
#pragma unroll
  for (int o2 = 0; o2 < 2; o2++) {
    const int ccg = g * 2 + o2;
    float sc[8], sh[8];
#pragma unroll
    for (int j = 0; j < 8; j++) {
      int ch = ccg * 8 + j;
      sc[j] = gamma[ch] * rstd;
      sh[j] = beta[ch] - mu * sc[j];
    }
#pragma unroll
    for (int m = 0; m < 4; m++) {
      us8 v;
#pragma unroll
      for (int j = 0; j < 8; j++) v[j] = f2bf(x[o2 * 8 + j][m] * sc[j] + sh[j]);
      *(us8*)(Xnt + (size_t)b * 524288 + (size_t)ccg * 8192 + (size_t)(4 * tid + m) * 8) = v;
    }
  }
}

// ---- gemm8p v2: 256x256, 8 waves (2Mx4N, 128x64/wave), 2 phases per BK=64 --
// r5 postmortem: quadrant-phases re-read fragments (48 ds_reads/K-tile) and
// used 8 barriers/K-tile -> lockstep LDS bursts, MfmaUtil 12%. v2 loads each
// fragment ONCE (24 reads/K-tile: PhA = A-half0 8 + B-all 8 kept live in
// regs; PhB = A-half1 8, B reused) with 32-MFMA clusters and 2 barriers/tile.
// Counted vmcnt never drained mid-loop: staging order [Aq0,Aq2,Bq0,Bq1 |
// Bq2,Bq3,Aq1,Aq3]; PhA-end vmcnt(4) releases this tile's late A quarters,
// PhB-end vmcnt(2) leaves next tile's late A in flight. lgkmcnt(0) +
// sched_barrier(0) before each MFMA cluster (rule #18). LDS 128KB, 1 blk/CU.
// Layouts identical to r5 (numerically verified): AR=1 A quarter =
// [8 kc][64 rows][8]; AR=0 / B: [64 rows][8 slots][8], slot = kc ^ (row&7)
// applied on GLOBAL src (LDS dest linear) and on ds_read.
template <int EPI, int NT, int AR>
__global__ __launch_bounds__(512, 2) void gemm8p(
    const UST* __restrict__ A, const UST* __restrict__ B, void* __restrict__ C,
    const float* __restrict__ bias, const float* __restrict__ extra, float scale,
    int K, int ldc, int rsA, int csA, long ssA, int rsB, long ssB,
    long zA, long zB, long zC) {
  __shared__ __align__(16) UST buf[65536];  // 128 KiB

  const int tid = threadIdx.x;
  int lin = blockIdx.x + NT * (blockIdx.y + gridDim.y * blockIdx.z);
  int T = gridDim.y * gridDim.z;
  int per = T >> 3;
  int g = lin & 7, idx = lin >> 3;
  int at = g * per + idx / NT;
  int x = idx % NT;
  const int m0 = (at % gridDim.y) * 256;
  const int z = at / gridDim.y;
  const int n0 = x * 256;

  const UST* Ab = A + (long)z * zA;
  const UST* Bb = B + (long)z * zB;

  const int w = tid >> 6, lane = tid & 63;
  const int quad = lane >> 4, l16 = lane & 15;
  const int wr = w >> 2, wc = w & 3;  // 2x4 waves, each 128(m) x 64(n)

  f32x4 acc[8][4];
#pragma unroll
  for (int i = 0; i < 8; i++)
#pragma unroll
    for (int j = 0; j < 4; j++) acc[i][j] = f32x4{0.f, 0.f, 0.f, 0.f};

  // staging pointers: pos 0=Aq0 1=Aq2 2=Bq0 3=Bq1 4=Bq2 5=Bq3 6=Aq1 7=Aq3
  const UST* gp[8];
  int lo[8];
  {
    const int lr = w * 8 + (lane >> 3);
    const int kcl = (lane & 7) ^ (lane >> 3);
#pragma unroll
    for (int p = 0; p < 8; p++) {
      int q;
      bool isA;
      if (p == 0) { q = 0; isA = true; }
      else if (p == 1) { q = 2; isA = true; }
      else if (p == 6) { q = 1; isA = true; }
      else if (p == 7) { q = 3; isA = true; }
      else { q = p - 2; isA = false; }
      if (isA) {
        if (AR) gp[p] = Ab + (size_t)(m0 + q * 64 + lane) * rsA + (size_t)w * csA;
        else    gp[p] = Ab + (size_t)(m0 + q * 64 + lr) * rsA + (size_t)kcl * csA;
        lo[p] = q * 4096 + w * 512;
      } else {
        gp[p] = Bb + (size_t)(n0 + q * 64 + lr) * rsB + (size_t)kcl * 8;
        lo[p] = 16384 + q * 4096 + w * 512;
      }
    }
  }

  // ds_read offsets (UST, within one dbuf)
  int aoffs[8][2], boffs[4][2];
#pragma unroll
  for (int i = 0; i < 8; i++) {
    int R = wr * 128 + i * 16 + l16;
    int q = R >> 6, lr = R & 63;
#pragma unroll
    for (int ks = 0; ks < 2; ks++) {
      int kc = ks * 4 + quad;
      aoffs[i][ks] = AR ? (q * 4096 + (kc * 64 + lr) * 8)
                        : (q * 4096 + (lr * 8 + (kc ^ (lr & 7))) * 8);
    }
  }
#pragma unroll
  for (int j = 0; j < 4; j++) {
    int R = wc * 64 + j * 16 + l16;
    int q = R >> 6, lr = R & 63;
#pragma unroll
    for (int ks = 0; ks < 2; ks++) {
      int kc = ks * 4 + quad;
      boffs[j][ks] = 16384 + q * 4096 + (lr * 8 + (kc ^ (lr & 7))) * 8;
    }
  }

  const int nk = K >> 6;  // K-tiles of 64

#define STG(P, SS) { gload16(gp[P], lb + lo[P]); gp[P] += (SS); }

  // prologue: stage tile 0; first 6 loads (Aq0,Aq2,B all) must land for PhA
  {
    UST* lb = buf;
    STG(0, ssA) STG(1, ssA) STG(2, ssB) STG(3, ssB)
    STG(4, ssB) STG(5, ssB) STG(6, ssA) STG(7, ssA)
  }
  asm volatile("s_waitcnt vmcnt(2)" ::: "memory");
  barrier_nowait();

  for (int t = 0; t < nk; ++t) {
    const UST* cb = buf + (t & 1) * 32768;
    UST* lb = buf + ((t + 1) & 1) * 32768;
    const bool stg = (t + 1 < nk);

    // ---- Phase A: A-half0 + ALL B (kept live for PhB) -> 32 MFMA ----
    bf16x8 a0[4][2], bb[4][2];
#pragma unroll
    for (int il = 0; il < 4; il++)
#pragma unroll
      for (int ks = 0; ks < 2; ks++)
        a0[il][ks] = *(const bf16x8*)(cb + aoffs[il][ks]);
#pragma unroll
    for (int j = 0; j < 4; j++)
#pragma unroll
      for (int ks = 0; ks < 2; ks++)
        bb[j][ks] = *(const bf16x8*)(cb + boffs[j][ks]);
    if (stg) { STG(0, ssA) STG(1, ssA) STG(2, ssB) STG(3, ssB) }
    asm volatile("s_waitcnt lgkmcnt(0)" ::: "memory");
    __builtin_amdgcn_sched_barrier(0);
    __builtin_amdgcn_s_setprio(1);
#pragma unroll
    for (int ks = 0; ks < 2; ks++)
#pragma unroll
      for (int il = 0; il < 4; il++)
#pragma unroll
        for (int j = 0; j < 4; j++)
          acc[il][j] = __builtin_amdgcn_mfma_f32_16x16x32_bf16(
              a0[il][ks], bb[j][ks], acc[il][j], 0, 0, 0);
    __builtin_amdgcn_s_setprio(0);
    // release this tile's late A quarters (Aq1,Aq3) for PhB's ds_reads
    if (stg) asm volatile("s_waitcnt vmcnt(4)" ::: "memory");
    else     asm volatile("s_waitcnt vmcnt(0)" ::: "memory");
    barrier_nowait();

    // ---- Phase B: A-half1, B reused from regs -> 32 MFMA ----
    bf16x8 a1[4][2];
#pragma unroll
    for (int il = 0; il < 4; il++)
#pragma unroll
      for (int ks = 0; ks < 2; ks++)
        a1[il][ks] = *(const bf16x8*)(cb + aoffs[4 + il][ks]);
    if (stg) { STG(4, ssB) STG(5, ssB) STG(6, ssA) STG(7, ssA) }
    asm volatile("s_waitcnt lgkmcnt(0)" ::: "memory");
    __builtin_amdgcn_sched_barrier(0);
    __builtin_amdgcn_s_setprio(1);
#pragma unroll
    for (int ks = 0; ks < 2; ks++)
#pragma unroll
      for (int il = 0; il < 4; il++)
#pragma unroll
        for (int j = 0; j < 4; j++)
          acc[4 + il][j] = __builtin_amdgcn_mfma_f32_16x16x32_bf16(
              a1[il][ks], bb[j][ks], acc[4 + il][j], 0, 0, 0);
    __builtin_amdgcn_s_setprio(0);
    // next tile's first 6 (Aq0,Aq2,B) must land; leave its Aq1,Aq3 in flight
    if (stg) asm volatile("s_waitcnt vmcnt(2)" ::: "memory");
    barrier_nowait();
  }
#undef STG

  // ---- epilogue: row = wr*128 + i*16 + quad*4 + r, col = wc*64 + j*16 + l16
  if constexpr (EPI == 7) {
    UST* Cb = (UST*)C + (long)z * zC;
    float* lrow = (float*)extra + (long)z * 1024;
#pragma unroll
    for (int h = 0; h < 2; ++h) {
      if (h) barrier_nowait();
      if (wr == h) {
#pragma unroll
        for (int i = 0; i < 8; i++)
#pragma unroll
          for (int j = 0; j < 4; j++)
#pragma unroll
            for (int r = 0; r < 4; r++) {
              float v = __expf(acc[i][j][r] * scale);
              buf[(i * 16 + quad * 4 + r) * 260 + wc * 64 + j * 16 + l16] = f2bf(v);
            }
      }
      sync_lds();
#pragma unroll
      for (int it = 0; it < 8; ++it) {
        int q = tid + it * 512;
        int row = q >> 5, colc = q & 31;
        us8 v = *(us8*)&buf[row * 260 + colc * 8];
        *(us8*)&Cb[(size_t)(m0 + h * 128 + row) * ldc + n0 + colc * 8] = v;
        float s = 0.f;
#pragma unroll
        for (int jj = 0; jj < 8; jj++) s += bf2f(v[jj]);
        s += __shfl_xor(s, 16); s += __shfl_xor(s, 8);
        s += __shfl_xor(s, 4); s += __shfl_xor(s, 2); s += __shfl_xor(s, 1);
        if ((lane & 31) == 0) atomicAdd(&lrow[m0 + h * 128 + row], s);
      }
    }
  }
}

// ---- gemm_bt v5 (proven): 128x128, 4 waves, gload_lds, depth-2 vmcnt(4) ----
template <int EPI, int NT, int AR, int BR>
__global__ __launch_bounds__(256, 4) void gemm_bt(
    const UST* __restrict__ A, const UST* __restrict__ B, void* __restrict__ C,
    const float* __restrict__ bias, const float* __restrict__ extra, float scale,
    int K, int ldc,
    int rsA, int csA, int ssA, int rsB, int csB, int ssB,
    long zA, long zB, long zC) {
  __shared__ __align__(16) UST buf[16384];

  const int tid = threadIdx.x;
  int m0, n0, z;
  if constexpr (NT > 0) {
    int lin = blockIdx.x + NT * (blockIdx.y + gridDim.y * blockIdx.z);
    int T = gridDim.y * gridDim.z;
    int per = T >> 3;
    int g = lin & 7, idx = lin >> 3;
    int at = g * per + idx / NT;
    int x = idx % NT;
    m0 = (at % gridDim.y) * 128; z = at / gridDim.y; n0 = x * 128;
  } else {
    m0 = blockIdx.y * 128; n0 = blockIdx.x * 128; z = blockIdx.z;
  }
  const UST* Ab = A + (long)z * zA;
  const UST* Bb = B + (long)z * zB;

  const int w = tid >> 6, lane = tid & 63;
  const int quad = lane >> 4, l16 = lane & 15;
  const int wm = w >> 1, wn = w & 1;

  f32x4 acc[4][4];
#pragma unroll
  for (int i = 0; i < 4; i++)
#pragma unroll
    for (int j = 0; j < 4; j++) acc[i][j] = f32x4{0.f, 0.f, 0.f, 0.f};

  const UST* gA[2];
  const UST* gB[2];
#pragma unroll
  for (int t = 0; t < 2; t++) {
    int q = t * 256 + w * 64 + lane;
    int row, kc;
    if constexpr (AR) { kc = q >> 7; row = q & 127; }
    else {
      row = q >> 2; int kk = q & 3;
      kc = kk ^ (((row >> 1) ^ (row >> 3)) & 3);
    }
    gA[t] = Ab + (size_t)(m0 + row) * rsA + (size_t)kc * csA;
  }
#pragma unroll
  for (int t = 0; t < 2; t++) {
    int q = t * 256 + w * 64 + lane;
    int row, kc;
    if constexpr (BR) { kc = q >> 7; row = q & 127; }
    else {
      row = q >> 2; int kk = q & 3;
      kc = kk ^ (((row >> 1) ^ (row >> 3)) & 3);
    }
    gB[t] = Bb + (size_t)(n0 + row) * rsB + (size_t)kc * csB;
  }
  int aoff[4], boff[4];
#pragma unroll
  for (int i = 0; i < 4; i++) {
    int R = wm * 64 + i * 16 + l16;
    if constexpr (AR) aoff[i] = quad * 1024 + R * 8;
    else {
      int s = ((R >> 1) ^ (R >> 3)) & 3;
      aoff[i] = R * 32 + (quad ^ s) * 8;
    }
  }
#pragma unroll
  for (int j = 0; j < 4; j++) {
    int R = wn * 64 + j * 16 + l16;
    if constexpr (BR) boff[j] = quad * 1024 + R * 8;
    else {
      int s = ((R >> 1) ^ (R >> 3)) & 3;
      boff[j] = R * 32 + (quad ^ s) * 8;
    }
  }

  const int nk = K >> 5;

#define STAGE(bb)                                   \
  {                                                 \
    UST* sA = buf + (bb) * 8192;                    \
    UST* sB = sA + 4096;                            \
    _Pragma("unroll") for (int t = 0; t < 2; t++) { \
      gload16(gA[t], sA + t * 2048 + w * 512);      \
      gA[t] += ssA;                                 \
    }                                               \
    _Pragma("unroll") for (int t = 0; t < 2; t++) { \
      gload16(gB[t], sB + t * 2048 + w * 512);      \
      gB[t] += ssB;                                 \
    }                                               \
  }

  STAGE(0)
  STAGE(1)

  for (int k = 0; k < nk; ++k) {
    if (k + 1 < nk) asm volatile("s_waitcnt vmcnt(4)" ::: "memory");
    else            asm volatile("s_waitcnt vmcnt(0)" ::: "memory");
    barrier_nowait();
    const UST* cA = buf + (k & 1) * 8192;
    const UST* cB = cA + 4096;
    bf16x8 af[4], bfr[4];
#pragma unroll
    for (int i = 0; i < 4; i++) af[i] = *(const bf16x8*)(cA + aoff[i]);
#pragma unroll
    for (int j = 0; j < 4; j++) bfr[j] = *(const bf16x8*)(cB + boff[j]);
    __builtin_amdgcn_s_setprio(1);
#pragma unroll
    for (int i = 0; i < 4; i++)
#pragma unroll
      for (int j = 0; j < 4; j++)
        acc[i][j] = __builtin_amdgcn_mfma_f32_16x16x32_bf16(af[i], bfr[j], acc[i][j], 0, 0, 0);
    __builtin_amdgcn_s_setprio(0);
    if (k + 2 < nk) {
      sync_lds();
      STAGE(k & 1)
    }
  }
  sync_lds();

  if constexpr (EPI == 4) {
    float* fbuf = (float*)buf;
    float* Cb = (float*)C + (long)z * zC;
    const float* Eb = extra + (long)z * zC;
#pragma unroll
    for (int p = 0; p < 4; ++p) {
      if (p) barrier_nowait();
      if (wm == (p >> 1)) {
#pragma unroll
        for (int ii = 0; ii < 2; ii++) {
          const int i = (p & 1) * 2 + ii;
#pragma unroll
          for (int j = 0; j < 4; j++)
#pragma unroll
            for (int r = 0; r < 4; r++)
              fbuf[(ii * 16 + quad * 4 + r) * 132 + wn * 64 + j * 16 + l16] = acc[i][j][r];
        }
      }
      sync_lds();
#pragma unroll
      for (int it = 0; it < 4; ++it) {
        int q = tid + it * 256;
        int row = q >> 5, colc = q & 31;
        int gr = m0 + p * 32 + row;
        size_t off = (size_t)gr * ldc + n0 + colc * 4;
        float4 v = *(float4*)&fbuf[row * 132 + colc * 4];
        float4 e = *(const float4*)&Eb[off];
        float bb = bias[gr];
        v.x += bb + e.x; v.y += bb + e.y; v.z += bb + e.z; v.w += bb + e.w;
        *(float4*)&Cb[off] = v;
      }
    }
  } else if constexpr (EPI == 8) {
    UST* Cb = (UST*)C + (long)z * zC;
    const float* lrow = bias + (long)z * 1024;
#pragma unroll
    for (int h = 0; h < 2; ++h) {
      if (h) barrier_nowait();
      if (wm == h) {
#pragma unroll
        for (int i = 0; i < 4; i++) {
          float rs[4];
#pragma unroll
          for (int r = 0; r < 4; r++)
            rs[r] = 1.0f / lrow[m0 + h * 64 + i * 16 + quad * 4 + r];
#pragma unroll
          for (int j = 0; j < 4; j++)
#pragma unroll
            for (int r = 0; r < 4; r++)
              buf[(i * 16 + quad * 4 + r) * 136 + wn * 64 + j * 16 + l16] =
                  f2bf(acc[i][j][r] * rs[r]);
        }
      }
      sync_lds();
#pragma unroll
      for (int it = 0; it < 4; ++it) {
        int q = tid + it * 256;
        int row = q >> 4, colc = q & 15;
        us8 v = *(us8*)&buf[row * 136 + colc * 8];
        *(us8*)&Cb[(size_t)(m0 + h * 64 + row) * ldc + n0 + colc * 8] = v;
      }
    }
  } else if constexpr (EPI == 7) {
    UST* Cb = (UST*)C + (long)z * zC;
    float* lrow = (float*)extra + (long)z * 1024;
#pragma unroll
    for (int h = 0; h < 2; ++h) {
      if (h) barrier_nowait();
      if (wm == h) {
#pragma unroll
        for (int i = 0; i < 4; i++)
#pragma unroll
          for (int j = 0; j < 4; j++)
#pragma unroll
            for (int r = 0; r < 4; r++) {
              float v = __expf(acc[i][j][r] * scale);
              buf[(i * 16 + quad * 4 + r) * 136 + wn * 64 + j * 16 + l16] = f2bf(v);
            }
      }
      sync_lds();
#pragma unroll
      for (int it = 0; it < 4; ++it) {
        int q = tid + it * 256;
        int row = q >> 4, colc = q & 15;
        us8 v = *(us8*)&buf[row * 136 + colc * 8];
        *(us8*)&Cb[(size_t)(m0 + h * 64 + row) * ldc + n0 + colc * 8] = v;
        float s = 0.f;
#pragma unroll
        for (int j = 0; j < 8; j++) s += bf2f(v[j]);
        s += __shfl_xor(s, 8); s += __shfl_xor(s, 4);
        s += __shfl_xor(s, 2); s += __shfl_xor(s, 1);
        if ((lane & 15) == 0) atomicAdd(&lrow[m0 + h * 64 + row], s);
      }
    }
  } else {  // EPI 6: QKV
    const bool vreg = (n0 >= 1024);
    if (!vreg) {
      UST* Cb = (UST*)C + (long)z * zC;
#pragma unroll
      for (int h = 0; h < 2; ++h) {
        if (h) barrier_nowait();
        if (wm == h) {
#pragma unroll
          for (int i = 0; i < 4; i++)
#pragma unroll
            for (int j = 0; j < 4; j++) {
              const float bc = bias[n0 + wn * 64 + j * 16 + l16];
#pragma unroll
              for (int r = 0; r < 4; r++)
                buf[(i * 16 + quad * 4 + r) * 136 + wn * 64 + j * 16 + l16] =
                    f2bf(acc[i][j][r] + bc);
            }
        }
        sync_lds();
#pragma unroll
        for (int it = 0; it < 4; ++it) {
          int q = tid + it * 256;
          int row = q >> 4, colc = q & 15;
          us8 v = *(us8*)&buf[row * 136 + colc * 8];
          *(us8*)&Cb[(size_t)(m0 + h * 64 + row) * ldc + n0 + colc * 8] = v;
        }
      }
    } else {
      UST* Vb = (UST*)extra + (long)z * 524288;
#pragma unroll
      for (int h = 0; h < 2; ++h) {
        if (h) barrier_nowait();
        if (wn == h) {
#pragma unroll
          for (int i = 0; i < 4; i++)
#pragma unroll
            for (int j = 0; j < 4; j++) {
              const float bc = bias[n0 + wn * 64 + j * 16 + l16];
              ushort4 sv;
              sv.x = f2bf(acc[i][j][0] + bc);
              sv.y = f2bf(acc[i][j][1] + bc);
              sv.z = f2bf(acc[i][j][2] + bc);
              sv.w = f2bf(acc[i][j][3] + bc);
              *(ushort4*)&buf[(j * 16 + l16) * 136 + wm * 64 + i * 16 + quad * 4] = sv;
            }
        }
        sync_lds();
#pragma unroll
        for (int it = 0; it < 4; ++it) {
          int q = tid + it * 256;
          int c = q >> 4, mc = q & 15;
          us8 v = *(us8*)&buf[c * 136 + mc * 8];
          *(us8*)&Vb[(size_t)(n0 - 1024 + h * 64 + c) * 1024 + m0 + mc * 8] = v;
        }
      }
    }
  }
#undef STAGE
}

extern "C" void kernel_launch(void* const* d_in, const int* in_sizes, int n_in,
                              void* d_out, int out_size, void* d_ws, size_t ws_size,
                              hipStream_t stream) {
  const float* inp   = (const float*)d_in[0];
  const float* gamma = (const float*)d_in[1];
  const float* beta  = (const float*)d_in[2];
  const float* Wq    = (const float*)d_in[3];
  const float* bq    = (const float*)d_in[4];
  const float* Wk    = (const float*)d_in[5];
  const float* bk    = (const float*)d_in[6];
  const float* Wv    = (const float*)d_in[7];
  const float* bv    = (const float*)d_in[8];
  const float* Wo    = (const float*)d_in[9];
  const float* bo    = (const float*)d_in[10];
  float* out = (float*)d_out;
  char* ws = (char*)d_ws;

  UST*   Xnt   = (UST*)(ws);                           // 16 MB; reused as At
  UST*   QKt   = (UST*)(ws + ((size_t)16 << 20));      // 32 MB (b,n,1024)
  UST*   V     = (UST*)(ws + ((size_t)48 << 20));      // 16 MB (b,c,m)
  UST*   P     = (UST*)(ws + ((size_t)64 << 20));      // 32 MB (b,n,m)
  float* bqkv  = (float*)(ws + ((size_t)96 << 20));    // 6 KB
  UST*   Wqkvb = (UST*)(ws + ((size_t)96 << 20) + 8192);  // 1.5 MB
  UST*   Wob   = Wqkvb + 786432;                       // 512 KB
  float* l     = (float*)(ws + ((size_t)100 << 20));   // 64 KB
  UST*   At    = Xnt;

  prep<<<784, 256, 0, stream>>>(
      inp, gamma, beta, Xnt,
      (const float4*)Wq, (const float4*)Wk, (const float4*)Wv, (const float4*)Wo,
      (ushort4*)Wqkvb, (ushort4*)Wob,
      (const float4*)bq, (const float4*)bk, (const float4*)bv, (float4*)bqkv,
      (float4*)l);

  // QKV (v5, proven): cols 0..1023 -> QKt ; cols 1024..1535 -> V^T
  gemm_bt<6, 12, 1, 0><<<dim3(12, 8, 16), 256, 0, stream>>>(
      Xnt, Wqkvb, QKt, bqkv, (const float*)V, 1.f,
      512, 1024, 8, 8192, 32768, 512, 8, 32, 524288, 0, 1048576);
  // P = exp(Q K^T * scale), row sums -> l   [EXPERIMENT: gemm8p v2]
  gemm8p<7, 4, 0><<<dim3(4, 4, 16), 512, 0, stream>>>(
      QKt, QKt + 512, P, nullptr, (const float*)l, 0.04419417382415922f,
      512, 1024, 1024, 8, 64, 1024, 64, 1048576, 1048576, 1048576);
  // At = (P V^T) / l[row]
  gemm_bt<8, 4, 0, 0><<<dim3(4, 8, 16), 256, 0, stream>>>(
      P, V, At, (const float*)l, nullptr, 1.f,
      1024, 512, 1024, 8, 32, 1024, 8, 32, 1048576, 524288, 524288);
  // out = Wo At^T + bo[row] + inp
  gemm_bt<4, 8, 0, 0><<<dim3(8, 4, 16), 256, 0, stream>>>(
      Wob, At, out, bo, inp, 1.f,
      512, 1024, 512, 8, 32, 512, 8, 32, 0, 524288, 524288);
}